// Round 2
// baseline (74271.899 us; speedup 1.0000x reference)
//
#include <hip/hip_runtime.h>
#include <stdint.h>
#include <stddef.h>

#define B 16
#define T 400
#define E 768
#define PDIM 256
#define H 1024
#define ADIM 128
#define LDIM 32
#define MDIM 80

typedef unsigned short u16;
typedef __attribute__((ext_vector_type(8))) short short8v;
typedef __attribute__((ext_vector_type(4))) float float4v;

__device__ __forceinline__ float bf2f(u16 u){
  union { uint32_t i; float f; } v; v.i = ((uint32_t)u) << 16; return v.f;
}
__device__ __forceinline__ u16 f2bf(float f){
  union { float f; uint32_t i; } v; v.f = f;
  uint32_t x = v.i;
  return (u16)((x + 0x7FFFu + ((x >> 16) & 1u)) >> 16);
}
__device__ __forceinline__ float fast_sig(float x){ return 1.f/(1.f+__expf(-x)); }
__device__ __forceinline__ float fast_tanh(float x){ float e=__expf(2.f*x); return 1.f - 2.f/(e+1.f); }

// dtype-flex loads: f32 ? fp32 : bf16
__device__ __forceinline__ float ld1(const void* p, size_t i, bool f32){
  if(f32){ float v; __builtin_memcpy(&v, (const float*)p + i, 4); return v; }
  u16 h; __builtin_memcpy(&h, (const u16*)p + i, 2); return bf2f(h);
}
__device__ __forceinline__ void ld4(const void* p, size_t i, float o[4], bool f32){
  if(f32){ __builtin_memcpy(o, (const float*)p + i, 16); }
  else {
    uint2 u; __builtin_memcpy(&u, (const u16*)p + i, 8);
    o[0]=bf2f((u16)(u.x & 0xffffu)); o[1]=bf2f((u16)(u.x >> 16));
    o[2]=bf2f((u16)(u.y & 0xffffu)); o[3]=bf2f((u16)(u.y >> 16));
  }
}
__device__ __forceinline__ void st1(void* p, size_t i, float v, bool f32){
  if(f32) ((float*)p)[i] = v; else ((u16*)p)[i] = f2bf(v);
}

// ---------------- dtype detect ----------------
__global__ void k_detect(const uint32_t* __restrict__ x, int* flag){
  uint32_t w = x[threadIdx.x];
  float v = bf2f((u16)(w & 0xffffu));
  int bad = (fabsf(v) < 1e4f) ? 0 : 1;   // NaN -> bad
  __shared__ int s[256];
  s[threadIdx.x] = bad;
  __syncthreads();
  for(int st=128; st>0; st>>=1){ if(threadIdx.x<st) s[threadIdx.x]+=s[threadIdx.x+st]; __syncthreads(); }
  if(threadIdx.x==0) *flag = (s[0] >= 8) ? 1 : 0;
}

__global__ void k_zero(float* p, int n){
  int i = blockIdx.x*256 + threadIdx.x;
  if(i < n) p[i] = 0.f;
}

// initial prenet on step_in = 0  ->  lstm_in[b][0:256]
__global__ void k_init_prenet(const void* w2, const void* b1, const void* b2,
                              float* lstm_in, const int* dtf){
  const bool f32 = (*dtf)!=0;
  __shared__ float p1[PDIM];
  int j = threadIdx.x;
  p1[j] = fmaxf(ld1(b1, j, f32), 0.f);
  __syncthreads();
  float acc = ld1(b2, j, f32);
  for(int k=0;k<PDIM;k+=4){
    float w[4]; ld4(w2, (size_t)j*PDIM+k, w, f32);
    acc += w[0]*p1[k]+w[1]*p1[k+1]+w[2]*p1[k+2]+w[3]*p1[k+3];
  }
  float p2 = fmaxf(acc, 0.f);
  for(int b=0;b<B;b++) lstm_in[b*H + j] = p2;
}

// Vh[b,t,a] = sum_e x[b,t,e] * Vw[a,e]
__global__ void k_vh(const void* __restrict__ x, const void* __restrict__ Vw,
                     float* __restrict__ Vh, const int* dtf){
  const bool f32 = (*dtf)!=0;
  int bt = blockIdx.x;
  __shared__ float xr[E];
  for(int i=threadIdx.x;i<E;i+=128) xr[i] = ld1(x, (size_t)bt*E + i, f32);
  __syncthreads();
  int a = threadIdx.x;
  float acc = 0.f;
  for(int k=0;k<E;k+=4){
    float w[4]; ld4(Vw, (size_t)a*E+k, w, f32);
    acc += w[0]*xr[k]+w[1]*xr[k+1]+w[2]*xr[k+2]+w[3]*xr[k+3];
  }
  Vh[(size_t)bt*ADIM + a] = acc;
}

// ------------- LSTM phase kernel (+ piggy-backed Uf blocks) -------------
__global__ __launch_bounds__(256) void k_lstm(
    const void* __restrict__ wih, const void* __restrict__ whh,
    const void* __restrict__ bih, const void* __restrict__ bhh,
    const float* __restrict__ in_x, const float* __restrict__ in_h,
    float* __restrict__ c_io, float* __restrict__ h_out,
    const float* __restrict__ cum, const void* __restrict__ Fw,
    const void* __restrict__ Uw, float* __restrict__ Uf, const int* dtf)
{
  const bool f32 = (*dtf)!=0;
  if(blockIdx.x < 1024){
    int j = blockIdx.x;
    int lane = threadIdx.x & 63;
    int wv = threadIdx.x >> 6;
    float acc[4][4];
#pragma unroll
    for(int g=0;g<4;g++)
#pragma unroll
      for(int bb=0;bb<4;bb++) acc[g][bb]=0.f;

#pragma unroll
    for(int it=0; it<4; it++){
      int k = it*256 + lane*4;
      float xi[4][4];
#pragma unroll
      for(int bb=0;bb<4;bb++) __builtin_memcpy(xi[bb], &in_x[(size_t)(wv*4+bb)*H + k], 16);
#pragma unroll
      for(int g=0;g<4;g++){
        float w[4]; ld4(wih, ((size_t)(g*H + j))*H + k, w, f32);
#pragma unroll
        for(int bb=0;bb<4;bb++)
          acc[g][bb] += w[0]*xi[bb][0] + w[1]*xi[bb][1] + w[2]*xi[bb][2] + w[3]*xi[bb][3];
      }
    }
#pragma unroll
    for(int it=0; it<4; it++){
      int k = it*256 + lane*4;
      float xi[4][4];
#pragma unroll
      for(int bb=0;bb<4;bb++) __builtin_memcpy(xi[bb], &in_h[(size_t)(wv*4+bb)*H + k], 16);
#pragma unroll
      for(int g=0;g<4;g++){
        float w[4]; ld4(whh, ((size_t)(g*H + j))*H + k, w, f32);
#pragma unroll
        for(int bb=0;bb<4;bb++)
          acc[g][bb] += w[0]*xi[bb][0] + w[1]*xi[bb][1] + w[2]*xi[bb][2] + w[3]*xi[bb][3];
      }
    }
#pragma unroll
    for(int off=1; off<64; off<<=1){
#pragma unroll
      for(int g=0;g<4;g++)
#pragma unroll
        for(int bb=0;bb<4;bb++)
          acc[g][bb] += __shfl_xor(acc[g][bb], off, 64);
    }
    if(lane == 0){
      float bsum[4];
#pragma unroll
      for(int g=0;g<4;g++) bsum[g] = ld1(bih, g*H+j, f32) + ld1(bhh, g*H+j, f32);
#pragma unroll
      for(int bb=0;bb<4;bb++){
        int b = wv*4+bb;
        float zi = acc[0][bb] + bsum[0];
        float zf = acc[1][bb] + bsum[1];
        float zg = acc[2][bb] + bsum[2];
        float zo = acc[3][bb] + bsum[3];
        float ig = fast_sig(zi), fg = fast_sig(zf);
        float gg = fast_tanh(zg), og = fast_sig(zo);
        float c = fg * c_io[(size_t)b*H+j] + ig*gg;
        c_io[(size_t)b*H+j] = c;
        h_out[(size_t)b*H+j] = og * fast_tanh(c);
      }
    }
  } else {
    int idx = blockIdx.x - 1024;            // 0..399
    int b = idx / 25, ch = idx % 25, t0 = ch*16;
    __shared__ float cumh[46];
    __shared__ float Fl[LDIM*31];
    __shared__ float Ul[ADIM*LDIM];
    __shared__ float loc[16*LDIM];
    int tid = threadIdx.x;
    if(tid < 46){ int g = t0 - 15 + tid; cumh[tid] = (g>=0 && g<T) ? cum[b*T+g] : 0.f; }
    for(int i=tid; i<LDIM*31; i+=256) Fl[i] = ld1(Fw, i, f32);
    for(int i=tid; i<ADIM*LDIM; i+=256) Ul[i] = ld1(Uw, i, f32);
    __syncthreads();
    for(int i=tid; i<16*LDIM; i+=256){
      int tl = i >> 5, l = i & 31;
      float s=0.f;
      for(int q=0;q<31;q++) s += cumh[tl+q]*Fl[l*31+q];
      loc[i] = s;
    }
    __syncthreads();
    int tl = tid >> 4, al = tid & 15;
    int t = t0 + tl;
#pragma unroll
    for(int aa=0; aa<8; aa++){
      int a = al*8 + aa;
      float s=0.f;
#pragma unroll
      for(int l=0;l<LDIM;l++) s += loc[tl*LDIM+l]*Ul[a*LDIM+l];
      Uf[((size_t)b*T + t)*ADIM + a] = s;
    }
  }
}

// ------------- step tail: attention (blocks 0..15) + proj/prenet (16..31) -------------
__global__ __launch_bounds__(256) void k_step_tail(int t,
    const float* __restrict__ h1, const float* __restrict__ att_r, float* __restrict__ att_w,
    float* __restrict__ lstm_in, float* __restrict__ cum,
    const float* __restrict__ Vh, const float* __restrict__ Uf,
    const void* __restrict__ x,
    const void* __restrict__ attW, const void* __restrict__ attWb, const void* __restrict__ attv,
    const void* __restrict__ projw, const void* __restrict__ projb,
    const void* __restrict__ pw1, const void* __restrict__ pb1,
    const void* __restrict__ pw2, const void* __restrict__ pb2,
    void* __restrict__ outp, const int* dtf)
{
  const bool f32 = (*dtf)!=0;
  int blk = blockIdx.x, tid = threadIdx.x;
  if(blk < 16){
    int b = blk;
    __shared__ float wsp[256];
    __shared__ float Ws[ADIM];
    __shared__ float vl[ADIM];
    __shared__ float el[T];
    __shared__ float red[256];
    {
      int a = tid >> 1, s = tid & 1;
      size_t base = (size_t)a*H + s*512;
      const float* hr = &h1[(size_t)b*H + s*512];
      float acc=0.f;
      for(int k=0;k<512;k+=4){
        float w[4]; ld4(attW, base+k, w, f32);
        acc += w[0]*hr[k]+w[1]*hr[k+1]+w[2]*hr[k+2]+w[3]*hr[k+3];
      }
      wsp[tid]=acc;
    }
    __syncthreads();
    if(tid < ADIM){ Ws[tid] = wsp[2*tid]+wsp[2*tid+1] + ld1(attWb, tid, f32); vl[tid] = ld1(attv, tid, f32); }
    __syncthreads();
    for(int tt=tid; tt<T; tt+=256){
      const float* vh = &Vh[((size_t)b*T+tt)*ADIM];
      const float* uf = &Uf[((size_t)b*T+tt)*ADIM];
      float acc=0.f;
      for(int a=0;a<ADIM;a+=4){
        float v4[4], u4[4];
        __builtin_memcpy(v4, &vh[a], 16);
        __builtin_memcpy(u4, &uf[a], 16);
        acc += vl[a+0]*fast_tanh(Ws[a+0]+v4[0]+u4[0]);
        acc += vl[a+1]*fast_tanh(Ws[a+1]+v4[1]+u4[1]);
        acc += vl[a+2]*fast_tanh(Ws[a+2]+v4[2]+u4[2]);
        acc += vl[a+3]*fast_tanh(Ws[a+3]+v4[3]+u4[3]);
      }
      el[tt]=acc;
    }
    __syncthreads();
    float mx = -1e30f;
    for(int tt=tid; tt<T; tt+=256) mx = fmaxf(mx, el[tt]);
    red[tid]=mx; __syncthreads();
    for(int s=128;s>0;s>>=1){ if(tid<s) red[tid]=fmaxf(red[tid],red[tid+s]); __syncthreads(); }
    mx = red[0]; __syncthreads();
    float sum=0.f;
    for(int tt=tid; tt<T; tt+=256){ float ex=__expf(el[tt]-mx); el[tt]=ex; sum+=ex; }
    red[tid]=sum; __syncthreads();
    for(int s=128;s>0;s>>=1){ if(tid<s) red[tid]+=red[tid+s]; __syncthreads(); }
    float inv = 1.f/red[0];
    __syncthreads();
    for(int tt=tid; tt<T; tt+=256){ float aw = el[tt]*inv; el[tt]=aw; cum[b*T+tt] += aw; }
    __syncthreads();
    for(int p = tid; p < E/2; p += 256){
      int e0 = p*2;
      float a0=0.f, a1=0.f;
      if(f32){
        const float* xb = (const float*)x + (size_t)b*T*E + e0;
        for(int tt=0;tt<T;tt++){
          float v2[2]; __builtin_memcpy(v2, &xb[(size_t)tt*E], 8);
          float aw = el[tt];
          a0 += aw * v2[0]; a1 += aw * v2[1];
        }
      } else {
        const u16* xb = (const u16*)x + (size_t)b*T*E + e0;
        for(int tt=0;tt<T;tt++){
          uint32_t u; __builtin_memcpy(&u, &xb[(size_t)tt*E], 4);
          float aw = el[tt];
          a0 += aw * bf2f((u16)(u & 0xffffu));
          a1 += aw * bf2f((u16)(u >> 16));
        }
      }
      att_w[b*E + e0] = a0; att_w[b*E + e0 + 1] = a1;
      lstm_in[b*H + PDIM + e0] = a0; lstm_in[b*H + PDIM + e0 + 1] = a1;
    }
  } else {
    int b = blk - 16;
    __shared__ float lin[H+E];
    __shared__ float pp[160];
    __shared__ float outl[MDIM];
    __shared__ float p1[PDIM];
    for(int i=tid;i<H;i+=256) lin[i] = h1[(size_t)b*H+i];
    for(int i=tid;i<E;i+=256) lin[H+i] = att_r[b*E+i];
    __syncthreads();
    if(tid < 160){
      int m = tid >> 1, s = tid & 1;
      size_t base = (size_t)m*1792 + s*896;
      const float* lr = &lin[s*896];
      float acc=0.f;
      for(int k=0;k<896;k+=4){
        float w[4]; ld4(projw, base+k, w, f32);
        acc += w[0]*lr[k]+w[1]*lr[k+1]+w[2]*lr[k+2]+w[3]*lr[k+3];
      }
      pp[tid]=acc;
    }
    __syncthreads();
    if(tid < MDIM){
      float o = pp[2*tid]+pp[2*tid+1] + ld1(projb, tid, f32);
      outl[tid]=o;
      st1(outp, ((size_t)b*T + t)*MDIM + tid, o, f32);
    }
    __syncthreads();
    {
      float acc = ld1(pb1, tid, f32);
      for(int k=0;k<MDIM;k+=4){
        float w[4]; ld4(pw1, (size_t)tid*MDIM+k, w, f32);
        acc += w[0]*outl[k]+w[1]*outl[k+1]+w[2]*outl[k+2]+w[3]*outl[k+3];
      }
      p1[tid] = fmaxf(acc,0.f);
    }
    __syncthreads();
    {
      float acc = ld1(pb2, tid, f32);
      for(int k=0;k<PDIM;k+=4){
        float w[4]; ld4(pw2, (size_t)tid*PDIM+k, w, f32);
        acc += w[0]*p1[k]+w[1]*p1[k+1]+w[2]*p1[k+2]+w[3]*p1[k+3];
      }
      lstm_in[b*H + tid] = fmaxf(acc,0.f);
    }
  }
}

// ------------- PostNet weight repack to MFMA A-fragment order -------------
__global__ void k_repack(const void* __restrict__ w, u16* __restrict__ wf, const int* dtf){
  const bool f32 = (*dtf)!=0;
  int blk = blockIdx.x;                   // kw*128 + ic*16 + ot
  int ot = blk & 15, ic = (blk >> 4) & 7, kw = blk >> 7;
  int lane = threadIdx.x;
  int o = ot*16 + (lane & 15);
  int i0 = ic*32 + (lane >> 4)*8;
  size_t dst = ((size_t)blk*64 + lane)*8;
#pragma unroll
  for(int jj=0;jj<8;jj++)
    wf[dst+jj] = f2bf(ld1(w, ((size_t)o*256 + (i0+jj))*5 + kw, f32));
}

// ------------- fused PostNet: one block per (b,t); mel lives in d_out -------------
__global__ __launch_bounds__(256) void k_postnet(
    const void* __restrict__ w1, const void* __restrict__ b1,
    const u16* __restrict__ wf2, const void* __restrict__ b2,
    const u16* __restrict__ wf3, const void* __restrict__ b3,
    const void* __restrict__ w4, const void* __restrict__ b4,
    void* __restrict__ out, const int* dtf)
{
  const bool f32 = (*dtf)!=0;
  __shared__ u16 YT[88*264];
  __shared__ float mell[84];
  __shared__ float w4l[256*5];
  __shared__ float red4[160];
  int bt = blockIdx.x;
  int tid = threadIdx.x;
  if(tid < 84) mell[tid] = (tid>=2 && tid<82) ? ld1(out, (size_t)bt*MDIM + tid-2, f32) : 0.f;
  for(int i=tid;i<256*5;i+=256) w4l[i] = ld1(w4, i, f32);
  for(int i=tid;i<4*264;i+=256){
    int r = i/264, c = i - r*264;
    int row = (r<2)? r : 80+r;
    YT[row*264 + c] = 0;
  }
  __syncthreads();
  // layer 1 (1 -> 256), thread = out channel
  {
    float wr[5];
#pragma unroll
    for(int q=0;q<5;q++) wr[q] = ld1(w1, tid*5+q, f32);
    float bb = ld1(b1, tid, f32);
    for(int m=0;m<MDIM;m++){
      float s = bb;
#pragma unroll
      for(int q=0;q<5;q++) s += wr[q]*mell[m+q];
      YT[(m+2)*264 + tid] = f2bf(fast_tanh(s));
    }
  }
  __syncthreads();
  int lane = tid & 63, wv = tid >> 6;
  int lr = lane & 15, quad = lane >> 4;
  const u16* WF[2] = {wf2, wf3};
  const void* BS[2] = {b2, b3};
#pragma unroll 1
  for(int layer=0; layer<2; layer++){
    float4v acc[4][5];
#pragma unroll
    for(int ot=0;ot<4;ot++){
      int ob = (wv*4+ot)*16 + quad*4;
#pragma unroll
      for(int mt=0;mt<5;mt++)
#pragma unroll
        for(int r=0;r<4;r++) acc[ot][mt][r] = ld1(BS[layer], ob + r, f32);
    }
    const u16* wf = WF[layer];
    for(int kw=0;kw<5;kw++){
      for(int ic=0;ic<8;ic++){
        short8v a[4];
#pragma unroll
        for(int ot=0;ot<4;ot++){
          size_t idx = ((size_t)(kw*128 + ic*16 + (wv*4+ot))*64 + lane)*8;
          __builtin_memcpy(&a[ot], &wf[idx], 16);
        }
        short8v bfr[5];
        int ib = ic*32 + quad*8;
#pragma unroll
        for(int mt=0;mt<5;mt++){
          int row = mt*16 + lr + kw;
          __builtin_memcpy(&bfr[mt], &YT[row*264 + ib], 16);
        }
#pragma unroll
        for(int ot=0;ot<4;ot++)
#pragma unroll
          for(int mt=0;mt<5;mt++)
            acc[ot][mt] = __builtin_amdgcn_mfma_f32_16x16x32_bf16(a[ot], bfr[mt], acc[ot][mt], 0,0,0);
      }
    }
    __syncthreads();
#pragma unroll
    for(int ot=0;ot<4;ot++){
      int ob = (wv*4+ot)*16 + quad*4;
#pragma unroll
      for(int mt=0;mt<5;mt++){
        int row = mt*16 + lr + 2;
        u16 pk[4];
#pragma unroll
        for(int r=0;r<4;r++) pk[r] = f2bf(fast_tanh(acc[ot][mt][r]));
        __builtin_memcpy(&YT[row*264 + ob], pk, 8);
      }
    }
    __syncthreads();
  }
  // layer 4 (256 -> 1) + residual
  if(tid < 160){
    int m = tid >> 1, s = tid & 1;
    float accv = 0.f;
    for(int i = s*128; i < s*128+128; i++){
#pragma unroll
      for(int q=0;q<5;q++) accv += w4l[i*5+q] * bf2f(YT[(m+q)*264 + i]);
    }
    red4[tid] = accv;
  }
  __syncthreads();
  if(tid < MDIM){
    float o = red4[2*tid] + red4[2*tid+1] + ld1(b4, 0, f32) + mell[tid+2];
    st1(out, (size_t)bt*MDIM + tid, o, f32);
  }
}

extern "C" void kernel_launch(void* const* d_in, const int* in_sizes, int n_in,
                              void* d_out, int out_size, void* d_ws, size_t ws_size,
                              hipStream_t stream)
{
  (void)in_sizes; (void)n_in; (void)out_size; (void)ws_size;
  const void* x    = d_in[0];
  const void* pw1  = d_in[1];
  const void* pb1  = d_in[2];
  const void* pw2  = d_in[3];
  const void* pb2  = d_in[4];
  const void* wih0 = d_in[5];
  const void* whh0 = d_in[6];
  const void* bih0 = d_in[7];
  const void* bhh0 = d_in[8];
  const void* wih1 = d_in[9];
  const void* whh1 = d_in[10];
  const void* bih1 = d_in[11];
  const void* bhh1 = d_in[12];
  const void* attW = d_in[13];
  const void* attWb= d_in[14];
  const void* attV = d_in[15];
  const void* attU = d_in[16];
  const void* attF = d_in[17];
  const void* attv = d_in[18];
  const void* projw= d_in[19];
  const void* projb= d_in[20];
  const void* pnw1 = d_in[23];
  const void* pnb1 = d_in[24];
  const void* pnw2 = d_in[25];
  const void* pnb2 = d_in[26];
  const void* pnw3 = d_in[27];
  const void* pnb3 = d_in[28];
  const void* pnw4 = d_in[29];
  const void* pnb4 = d_in[30];

  float* base = (float*)d_ws;
  size_t off = 4;                           // slot 0..3: dtype flag (16B keeps alignment)
  int* dtf = (int*)d_ws;
  float* Vh   = base + off; off += (size_t)B*T*ADIM;
  float* Uf   = base + off; off += (size_t)B*T*ADIM;
  float* h0a  = base + off; off += B*H;
  float* h0b  = base + off; off += B*H;
  float* h1a  = base + off; off += B*H;
  float* h1b  = base + off; off += B*H;
  float* c0   = base + off; off += B*H;
  float* c1   = base + off; off += B*H;
  float* att0 = base + off; off += B*E;
  float* att1 = base + off; off += B*E;
  float* lstm_in = base + off; off += B*H;
  float* cum  = base + off; off += B*T;
  u16* wf2 = (u16*)(base + off); off += (5*8*16*64*8)/2;
  u16* wf3 = (u16*)(base + off); off += (5*8*16*64*8)/2;

  k_detect<<<1, 256, 0, stream>>>((const uint32_t*)x, dtf);
  int nzero = 6*B*H + 2*B*E + B*H + B*T;
  k_zero<<<(nzero+255)/256, 256, 0, stream>>>(h0a, nzero);
  k_init_prenet<<<1, 256, 0, stream>>>(pw2, pb1, pb2, lstm_in, dtf);
  k_vh<<<B*T, 128, 0, stream>>>(x, attV, Vh, dtf);
  k_repack<<<640, 64, 0, stream>>>(pnw2, wf2, dtf);
  k_repack<<<640, 64, 0, stream>>>(pnw3, wf3, dtf);

  for(int t=0; t<T; t++){
    float* h0r = (t&1)? h0b : h0a;
    float* h0w = (t&1)? h0a : h0b;
    float* h1r = (t&1)? h1b : h1a;
    float* h1w = (t&1)? h1a : h1b;
    float* attr = (t&1)? att1 : att0;
    float* attw = (t&1)? att0 : att1;
    k_lstm<<<1424, 256, 0, stream>>>(wih0, whh0, bih0, bhh0, lstm_in, h0r, c0, h0w,
                                     cum, attF, attU, Uf, dtf);
    k_lstm<<<1024, 256, 0, stream>>>(wih1, whh1, bih1, bhh1, h0w, h1r, c1, h1w,
                                     cum, attF, attU, Uf, dtf);
    k_step_tail<<<32, 256, 0, stream>>>(t, h1w, attr, attw, lstm_in, cum, Vh, Uf, x,
                                        attW, attWb, attv, projw, projb,
                                        pw1, pb1, pw2, pb2, d_out, dtf);
  }
  k_postnet<<<B*T, 256, 0, stream>>>(pnw1, pnb1, wf2, pnb2, wf3, pnb3,
                                     pnw4, pnb4, d_out, dtf);
}

// Round 3
// 58401.599 us; speedup vs baseline: 1.2717x; 1.2717x over previous
//
#include <hip/hip_runtime.h>
#include <stdint.h>
#include <stddef.h>

#define B 16
#define T 400
#define E 768
#define PDIM 256
#define H 1024
#define ADIM 128
#define LDIM 32
#define MDIM 80

typedef unsigned short u16;
typedef __attribute__((ext_vector_type(8))) short short8v;
typedef __attribute__((ext_vector_type(4))) float float4v;

__device__ __forceinline__ float bf2f(u16 u){
  union { uint32_t i; float f; } v; v.i = ((uint32_t)u) << 16; return v.f;
}
__device__ __forceinline__ u16 f2bf(float f){
  union { float f; uint32_t i; } v; v.f = f;
  uint32_t x = v.i;
  return (u16)((x + 0x7FFFu + ((x >> 16) & 1u)) >> 16);
}
__device__ __forceinline__ float fast_sig(float x){ return 1.f/(1.f+__expf(-x)); }
__device__ __forceinline__ float fast_tanh(float x){ float e=__expf(2.f*x); return 1.f - 2.f/(e+1.f); }

// compile-time specialized loads
template<bool F32>
__device__ __forceinline__ float ld1(const void* p, size_t i){
  if constexpr(F32){ float v; __builtin_memcpy(&v, (const float*)p + i, 4); return v; }
  else { u16 h; __builtin_memcpy(&h, (const u16*)p + i, 2); return bf2f(h); }
}
template<bool F32>
__device__ __forceinline__ void ld4(const void* p, size_t i, float o[4]){
  if constexpr(F32){ __builtin_memcpy(o, (const float*)p + i, 16); }
  else {
    uint2 u; __builtin_memcpy(&u, (const u16*)p + i, 8);
    o[0]=bf2f((u16)(u.x & 0xffffu)); o[1]=bf2f((u16)(u.x >> 16));
    o[2]=bf2f((u16)(u.y & 0xffffu)); o[3]=bf2f((u16)(u.y >> 16));
  }
}
template<bool F32>
__device__ __forceinline__ void st1(void* p, size_t i, float v){
  if constexpr(F32) ((float*)p)[i] = v; else ((u16*)p)[i] = f2bf(v);
}

// ---------------- dtype detect ----------------
__global__ void k_detect(const uint32_t* __restrict__ x, int* flag){
  uint32_t w = x[threadIdx.x];
  float v = bf2f((u16)(w & 0xffffu));
  int bad = (fabsf(v) < 1e4f) ? 0 : 1;   // NaN -> bad
  __shared__ int s[256];
  s[threadIdx.x] = bad;
  __syncthreads();
  for(int st=128; st>0; st>>=1){ if(threadIdx.x<st) s[threadIdx.x]+=s[threadIdx.x+st]; __syncthreads(); }
  if(threadIdx.x==0) *flag = (s[0] >= 8) ? 1 : 0;
}

__global__ void k_zero(float* p, int n){
  int i = blockIdx.x*256 + threadIdx.x;
  if(i < n) p[i] = 0.f;
}

// ---------------- init prenet ----------------
template<bool F32>
__device__ __forceinline__ void init_prenet_body(const void* w2, const void* b1, const void* b2,
                                                 float* lstm_in){
  __shared__ float p1[PDIM];
  int j = threadIdx.x;
  p1[j] = fmaxf(ld1<F32>(b1, j), 0.f);
  __syncthreads();
  float acc = ld1<F32>(b2, j);
  for(int k=0;k<PDIM;k+=4){
    float w[4]; ld4<F32>(w2, (size_t)j*PDIM+k, w);
    acc += w[0]*p1[k]+w[1]*p1[k+1]+w[2]*p1[k+2]+w[3]*p1[k+3];
  }
  float p2 = fmaxf(acc, 0.f);
  for(int b=0;b<B;b++) lstm_in[b*H + j] = p2;
}
__global__ void k_init_prenet(const void* w2, const void* b1, const void* b2,
                              float* lstm_in, const int* dtf){
  if(*dtf) init_prenet_body<true>(w2,b1,b2,lstm_in);
  else     init_prenet_body<false>(w2,b1,b2,lstm_in);
}

// ---------------- Vh ----------------
template<bool F32>
__device__ __forceinline__ void vh_body(const void* __restrict__ x, const void* __restrict__ Vw,
                                        float* __restrict__ Vh){
  int bt = blockIdx.x;
  __shared__ float xr[E];
  for(int i=threadIdx.x;i<E;i+=128) xr[i] = ld1<F32>(x, (size_t)bt*E + i);
  __syncthreads();
  int a = threadIdx.x;
  float acc = 0.f;
#pragma unroll 4
  for(int k=0;k<E;k+=4){
    float w[4]; ld4<F32>(Vw, (size_t)a*E+k, w);
    acc += w[0]*xr[k]+w[1]*xr[k+1]+w[2]*xr[k+2]+w[3]*xr[k+3];
  }
  Vh[(size_t)bt*ADIM + a] = acc;
}
__global__ void k_vh(const void* __restrict__ x, const void* __restrict__ Vw,
                     float* __restrict__ Vh, const int* dtf){
  if(*dtf) vh_body<true>(x,Vw,Vh); else vh_body<false>(x,Vw,Vh);
}

// ------------- LSTM phase (+ piggy-backed Uf blocks) -------------
template<bool F32>
__device__ __forceinline__ void lstm_body(
    const void* __restrict__ wih, const void* __restrict__ whh,
    const void* __restrict__ bih, const void* __restrict__ bhh,
    const float* __restrict__ in_x, const float* __restrict__ in_h,
    float* __restrict__ c_io, float* __restrict__ h_out,
    const float* __restrict__ cum, const void* __restrict__ Fw,
    const void* __restrict__ Uw, float* __restrict__ Uf)
{
  if(blockIdx.x < 1024){
    int j = blockIdx.x;
    int lane = threadIdx.x & 63;
    int wv = threadIdx.x >> 6;
    float acc[4][4];
#pragma unroll
    for(int g=0;g<4;g++)
#pragma unroll
      for(int bb=0;bb<4;bb++) acc[g][bb]=0.f;

#pragma unroll
    for(int it=0; it<4; it++){
      int k = it*256 + lane*4;
      float xi[4][4];
#pragma unroll
      for(int bb=0;bb<4;bb++) __builtin_memcpy(xi[bb], &in_x[(size_t)(wv*4+bb)*H + k], 16);
#pragma unroll
      for(int g=0;g<4;g++){
        float w[4]; ld4<F32>(wih, ((size_t)(g*H + j))*H + k, w);
#pragma unroll
        for(int bb=0;bb<4;bb++)
          acc[g][bb] += w[0]*xi[bb][0] + w[1]*xi[bb][1] + w[2]*xi[bb][2] + w[3]*xi[bb][3];
      }
    }
#pragma unroll
    for(int it=0; it<4; it++){
      int k = it*256 + lane*4;
      float xi[4][4];
#pragma unroll
      for(int bb=0;bb<4;bb++) __builtin_memcpy(xi[bb], &in_h[(size_t)(wv*4+bb)*H + k], 16);
#pragma unroll
      for(int g=0;g<4;g++){
        float w[4]; ld4<F32>(whh, ((size_t)(g*H + j))*H + k, w);
#pragma unroll
        for(int bb=0;bb<4;bb++)
          acc[g][bb] += w[0]*xi[bb][0] + w[1]*xi[bb][1] + w[2]*xi[bb][2] + w[3]*xi[bb][3];
      }
    }
#pragma unroll
    for(int off=1; off<64; off<<=1){
#pragma unroll
      for(int g=0;g<4;g++)
#pragma unroll
        for(int bb=0;bb<4;bb++)
          acc[g][bb] += __shfl_xor(acc[g][bb], off, 64);
    }
    if(lane == 0){
      float bsum[4];
#pragma unroll
      for(int g=0;g<4;g++) bsum[g] = ld1<F32>(bih, g*H+j) + ld1<F32>(bhh, g*H+j);
#pragma unroll
      for(int bb=0;bb<4;bb++){
        int b = wv*4+bb;
        float zi = acc[0][bb] + bsum[0];
        float zf = acc[1][bb] + bsum[1];
        float zg = acc[2][bb] + bsum[2];
        float zo = acc[3][bb] + bsum[3];
        float ig = fast_sig(zi), fg = fast_sig(zf);
        float gg = fast_tanh(zg), og = fast_sig(zo);
        float c = fg * c_io[(size_t)b*H+j] + ig*gg;
        c_io[(size_t)b*H+j] = c;
        h_out[(size_t)b*H+j] = og * fast_tanh(c);
      }
    }
  } else {
    int idx = blockIdx.x - 1024;            // 0..399
    int b = idx / 25, ch = idx % 25, t0 = ch*16;
    __shared__ float cumh[46];
    __shared__ float Fl[LDIM*31];
    __shared__ float Ul[ADIM*LDIM];
    __shared__ float loc[16*LDIM];
    int tid = threadIdx.x;
    if(tid < 46){ int g = t0 - 15 + tid; cumh[tid] = (g>=0 && g<T) ? cum[b*T+g] : 0.f; }
    for(int i=tid; i<LDIM*31; i+=256) Fl[i] = ld1<F32>(Fw, i);
    for(int i=tid; i<ADIM*LDIM; i+=256) Ul[i] = ld1<F32>(Uw, i);
    __syncthreads();
    for(int i=tid; i<16*LDIM; i+=256){
      int tl = i >> 5, l = i & 31;
      float s=0.f;
      for(int q=0;q<31;q++) s += cumh[tl+q]*Fl[l*31+q];
      loc[i] = s;
    }
    __syncthreads();
    int tl = tid >> 4, al = tid & 15;
    int t = t0 + tl;
#pragma unroll
    for(int aa=0; aa<8; aa++){
      int a = al*8 + aa;
      float s=0.f;
#pragma unroll
      for(int l=0;l<LDIM;l++) s += loc[tl*LDIM+l]*Ul[a*LDIM+l];
      Uf[((size_t)b*T + t)*ADIM + a] = s;
    }
  }
}
__global__ __launch_bounds__(256) void k_lstm(
    const void* wih, const void* whh, const void* bih, const void* bhh,
    const float* in_x, const float* in_h, float* c_io, float* h_out,
    const float* cum, const void* Fw, const void* Uw, float* Uf, const int* dtf)
{
  if(*dtf) lstm_body<true>(wih,whh,bih,bhh,in_x,in_h,c_io,h_out,cum,Fw,Uw,Uf);
  else     lstm_body<false>(wih,whh,bih,bhh,in_x,in_h,c_io,h_out,cum,Fw,Uw,Uf);
}

// ------------- step tail -------------
template<bool F32>
__device__ __forceinline__ void tail_body(int t,
    const float* __restrict__ h1, const float* __restrict__ att_r, float* __restrict__ att_w,
    float* __restrict__ lstm_in, float* __restrict__ cum,
    const float* __restrict__ Vh, const float* __restrict__ Uf,
    const void* __restrict__ x,
    const void* __restrict__ attW, const void* __restrict__ attWb, const void* __restrict__ attv,
    const void* __restrict__ projw, const void* __restrict__ projb,
    const void* __restrict__ pw1, const void* __restrict__ pb1,
    const void* __restrict__ pw2, const void* __restrict__ pb2,
    void* __restrict__ outp)
{
  int blk = blockIdx.x, tid = threadIdx.x;
  if(blk < 16){
    int b = blk;
    __shared__ float wsp[256];
    __shared__ float Ws[ADIM];
    __shared__ float vl[ADIM];
    __shared__ float el[T];
    __shared__ float red[256];
    {
      int a = tid >> 1, s = tid & 1;
      size_t base = (size_t)a*H + s*512;
      const float* hr = &h1[(size_t)b*H + s*512];
      float acc=0.f;
#pragma unroll 4
      for(int k=0;k<512;k+=4){
        float w[4]; ld4<F32>(attW, base+k, w);
        acc += w[0]*hr[k]+w[1]*hr[k+1]+w[2]*hr[k+2]+w[3]*hr[k+3];
      }
      wsp[tid]=acc;
    }
    __syncthreads();
    if(tid < ADIM){ Ws[tid] = wsp[2*tid]+wsp[2*tid+1] + ld1<F32>(attWb, tid); vl[tid] = ld1<F32>(attv, tid); }
    __syncthreads();
    for(int tt=tid; tt<T; tt+=256){
      const float* vh = &Vh[((size_t)b*T+tt)*ADIM];
      const float* uf = &Uf[((size_t)b*T+tt)*ADIM];
      float acc=0.f;
#pragma unroll 4
      for(int a=0;a<ADIM;a+=4){
        float v4[4], u4[4];
        __builtin_memcpy(v4, &vh[a], 16);
        __builtin_memcpy(u4, &uf[a], 16);
        acc += vl[a+0]*fast_tanh(Ws[a+0]+v4[0]+u4[0]);
        acc += vl[a+1]*fast_tanh(Ws[a+1]+v4[1]+u4[1]);
        acc += vl[a+2]*fast_tanh(Ws[a+2]+v4[2]+u4[2]);
        acc += vl[a+3]*fast_tanh(Ws[a+3]+v4[3]+u4[3]);
      }
      el[tt]=acc;
    }
    __syncthreads();
    float mx = -1e30f;
    for(int tt=tid; tt<T; tt+=256) mx = fmaxf(mx, el[tt]);
    red[tid]=mx; __syncthreads();
    for(int s=128;s>0;s>>=1){ if(tid<s) red[tid]=fmaxf(red[tid],red[tid+s]); __syncthreads(); }
    mx = red[0]; __syncthreads();
    float sum=0.f;
    for(int tt=tid; tt<T; tt+=256){ float ex=__expf(el[tt]-mx); el[tt]=ex; sum+=ex; }
    red[tid]=sum; __syncthreads();
    for(int s=128;s>0;s>>=1){ if(tid<s) red[tid]+=red[tid+s]; __syncthreads(); }
    float inv = 1.f/red[0];
    __syncthreads();
    for(int tt=tid; tt<T; tt+=256){ float aw = el[tt]*inv; el[tt]=aw; cum[b*T+tt] += aw; }
    __syncthreads();
    // ctx: lane-per-column, coalesced
    {
      float a0=0.f, a1=0.f, a2=0.f;
      const size_t xb = (size_t)b*T*E;
#pragma unroll 4
      for(int tt=0; tt<T; tt++){
        float aw = el[tt];
        size_t base = xb + (size_t)tt*E + tid;
        a0 += aw * ld1<F32>(x, base);
        a1 += aw * ld1<F32>(x, base+256);
        a2 += aw * ld1<F32>(x, base+512);
      }
      att_w[b*E + tid]       = a0;
      att_w[b*E + tid + 256] = a1;
      att_w[b*E + tid + 512] = a2;
      lstm_in[b*H + PDIM + tid]       = a0;
      lstm_in[b*H + PDIM + tid + 256] = a1;
      lstm_in[b*H + PDIM + tid + 512] = a2;
    }
  } else {
    int b = blk - 16;
    __shared__ float lin[H+E];
    __shared__ float pp[160];
    __shared__ float outl[MDIM];
    __shared__ float p1[PDIM];
    for(int i=tid;i<H;i+=256) lin[i] = h1[(size_t)b*H+i];
    for(int i=tid;i<E;i+=256) lin[H+i] = att_r[b*E+i];
    __syncthreads();
    if(tid < 160){
      int m = tid >> 1, s = tid & 1;
      size_t base = (size_t)m*1792 + s*896;
      const float* lr = &lin[s*896];
      float acc=0.f;
#pragma unroll 4
      for(int k=0;k<896;k+=4){
        float w[4]; ld4<F32>(projw, base+k, w);
        acc += w[0]*lr[k]+w[1]*lr[k+1]+w[2]*lr[k+2]+w[3]*lr[k+3];
      }
      pp[tid]=acc;
    }
    __syncthreads();
    if(tid < MDIM){
      float o = pp[2*tid]+pp[2*tid+1] + ld1<F32>(projb, tid);
      outl[tid]=o;
      st1<F32>(outp, ((size_t)b*T + t)*MDIM + tid, o);
    }
    __syncthreads();
    {
      float acc = ld1<F32>(pb1, tid);
#pragma unroll
      for(int k=0;k<MDIM;k+=4){
        float w[4]; ld4<F32>(pw1, (size_t)tid*MDIM+k, w);
        acc += w[0]*outl[k]+w[1]*outl[k+1]+w[2]*outl[k+2]+w[3]*outl[k+3];
      }
      p1[tid] = fmaxf(acc,0.f);
    }
    __syncthreads();
    {
      float acc = ld1<F32>(pb2, tid);
#pragma unroll 4
      for(int k=0;k<PDIM;k+=4){
        float w[4]; ld4<F32>(pw2, (size_t)tid*PDIM+k, w);
        acc += w[0]*p1[k]+w[1]*p1[k+1]+w[2]*p1[k+2]+w[3]*p1[k+3];
      }
      lstm_in[b*H + tid] = fmaxf(acc,0.f);
    }
  }
}
__global__ __launch_bounds__(256) void k_step_tail(int t,
    const float* h1, const float* att_r, float* att_w,
    float* lstm_in, float* cum, const float* Vh, const float* Uf,
    const void* x, const void* attW, const void* attWb, const void* attv,
    const void* projw, const void* projb,
    const void* pw1, const void* pb1, const void* pw2, const void* pb2,
    void* outp, const int* dtf)
{
  if(*dtf) tail_body<true>(t,h1,att_r,att_w,lstm_in,cum,Vh,Uf,x,attW,attWb,attv,projw,projb,pw1,pb1,pw2,pb2,outp);
  else     tail_body<false>(t,h1,att_r,att_w,lstm_in,cum,Vh,Uf,x,attW,attWb,attv,projw,projb,pw1,pb1,pw2,pb2,outp);
}

// ------------- PostNet weight repack -------------
template<bool F32>
__device__ __forceinline__ void repack_body(const void* __restrict__ w, u16* __restrict__ wf){
  int blk = blockIdx.x;                   // kw*128 + ic*16 + ot
  int ot = blk & 15, ic = (blk >> 4) & 7, kw = blk >> 7;
  int lane = threadIdx.x;
  int o = ot*16 + (lane & 15);
  int i0 = ic*32 + (lane >> 4)*8;
  size_t dst = ((size_t)blk*64 + lane)*8;
#pragma unroll
  for(int jj=0;jj<8;jj++)
    wf[dst+jj] = f2bf(ld1<F32>(w, ((size_t)o*256 + (i0+jj))*5 + kw));
}
__global__ void k_repack(const void* w, u16* wf, const int* dtf){
  if(*dtf) repack_body<true>(w,wf); else repack_body<false>(w,wf);
}

// ------------- fused PostNet: one block per (b,t); mel lives in d_out -------------
template<bool F32>
__device__ __forceinline__ void postnet_body(
    const void* __restrict__ w1, const void* __restrict__ b1,
    const u16* __restrict__ wf2, const void* __restrict__ b2,
    const u16* __restrict__ wf3, const void* __restrict__ b3,
    const void* __restrict__ w4, const void* __restrict__ b4,
    void* __restrict__ out)
{
  __shared__ u16 YT[88*264];
  __shared__ float mell[84];
  __shared__ float w4l[256*5];
  __shared__ float red4[160];
  int bt = blockIdx.x;
  int tid = threadIdx.x;
  if(tid < 84) mell[tid] = (tid>=2 && tid<82) ? ld1<F32>(out, (size_t)bt*MDIM + tid-2) : 0.f;
  for(int i=tid;i<256*5;i+=256) w4l[i] = ld1<F32>(w4, i);
  for(int i=tid;i<4*264;i+=256){
    int r = i/264, c = i - r*264;
    int row = (r<2)? r : 80+r;
    YT[row*264 + c] = 0;
  }
  __syncthreads();
  {
    float wr[5];
#pragma unroll
    for(int q=0;q<5;q++) wr[q] = ld1<F32>(w1, tid*5+q);
    float bb = ld1<F32>(b1, tid);
    for(int m=0;m<MDIM;m++){
      float s = bb;
#pragma unroll
      for(int q=0;q<5;q++) s += wr[q]*mell[m+q];
      YT[(m+2)*264 + tid] = f2bf(fast_tanh(s));
    }
  }
  __syncthreads();
  int lane = tid & 63, wv = tid >> 6;
  int lr = lane & 15, quad = lane >> 4;
  const u16* WF[2] = {wf2, wf3};
  const void* BS[2] = {b2, b3};
#pragma unroll 1
  for(int layer=0; layer<2; layer++){
    float4v acc[4][5];
#pragma unroll
    for(int ot=0;ot<4;ot++){
      int ob = (wv*4+ot)*16 + quad*4;
#pragma unroll
      for(int mt=0;mt<5;mt++)
#pragma unroll
        for(int r=0;r<4;r++) acc[ot][mt][r] = ld1<F32>(BS[layer], ob + r);
    }
    const u16* wf = WF[layer];
    for(int kw=0;kw<5;kw++){
      for(int ic=0;ic<8;ic++){
        short8v a[4];
#pragma unroll
        for(int ot=0;ot<4;ot++){
          size_t idx = ((size_t)(kw*128 + ic*16 + (wv*4+ot))*64 + lane)*8;
          __builtin_memcpy(&a[ot], &wf[idx], 16);
        }
        short8v bfr[5];
        int ib = ic*32 + quad*8;
#pragma unroll
        for(int mt=0;mt<5;mt++){
          int row = mt*16 + lr + kw;
          __builtin_memcpy(&bfr[mt], &YT[row*264 + ib], 16);
        }
#pragma unroll
        for(int ot=0;ot<4;ot++)
#pragma unroll
          for(int mt=0;mt<5;mt++)
            acc[ot][mt] = __builtin_amdgcn_mfma_f32_16x16x32_bf16(a[ot], bfr[mt], acc[ot][mt], 0,0,0);
      }
    }
    __syncthreads();
#pragma unroll
    for(int ot=0;ot<4;ot++){
      int ob = (wv*4+ot)*16 + quad*4;
#pragma unroll
      for(int mt=0;mt<5;mt++){
        int row = mt*16 + lr + 2;
        u16 pk[4];
#pragma unroll
        for(int r=0;r<4;r++) pk[r] = f2bf(fast_tanh(acc[ot][mt][r]));
        __builtin_memcpy(&YT[row*264 + ob], pk, 8);
      }
    }
    __syncthreads();
  }
  if(tid < 160){
    int m = tid >> 1, s = tid & 1;
    float accv = 0.f;
    for(int i = s*128; i < s*128+128; i++){
#pragma unroll
      for(int q=0;q<5;q++) accv += w4l[i*5+q] * bf2f(YT[(m+q)*264 + i]);
    }
    red4[tid] = accv;
  }
  __syncthreads();
  if(tid < MDIM){
    float o = red4[2*tid] + red4[2*tid+1] + ld1<F32>(b4, 0) + mell[tid+2];
    st1<F32>(out, (size_t)bt*MDIM + tid, o);
  }
}
__global__ __launch_bounds__(256) void k_postnet(
    const void* w1, const void* b1, const u16* wf2, const void* b2,
    const u16* wf3, const void* b3, const void* w4, const void* b4,
    void* out, const int* dtf)
{
  if(*dtf) postnet_body<true>(w1,b1,wf2,b2,wf3,b3,w4,b4,out);
  else     postnet_body<false>(w1,b1,wf2,b2,wf3,b3,w4,b4,out);
}

extern "C" void kernel_launch(void* const* d_in, const int* in_sizes, int n_in,
                              void* d_out, int out_size, void* d_ws, size_t ws_size,
                              hipStream_t stream)
{
  (void)in_sizes; (void)n_in; (void)out_size; (void)ws_size;
  const void* x    = d_in[0];
  const void* pw1  = d_in[1];
  const void* pb1  = d_in[2];
  const void* pw2  = d_in[3];
  const void* pb2  = d_in[4];
  const void* wih0 = d_in[5];
  const void* whh0 = d_in[6];
  const void* bih0 = d_in[7];
  const void* bhh0 = d_in[8];
  const void* wih1 = d_in[9];
  const void* whh1 = d_in[10];
  const void* bih1 = d_in[11];
  const void* bhh1 = d_in[12];
  const void* attW = d_in[13];
  const void* attWb= d_in[14];
  const void* attV = d_in[15];
  const void* attU = d_in[16];
  const void* attF = d_in[17];
  const void* attv = d_in[18];
  const void* projw= d_in[19];
  const void* projb= d_in[20];
  const void* pnw1 = d_in[23];
  const void* pnb1 = d_in[24];
  const void* pnw2 = d_in[25];
  const void* pnb2 = d_in[26];
  const void* pnw3 = d_in[27];
  const void* pnb3 = d_in[28];
  const void* pnw4 = d_in[29];
  const void* pnb4 = d_in[30];

  float* base = (float*)d_ws;
  size_t off = 4;                           // slot 0..3: dtype flag
  int* dtf = (int*)d_ws;
  float* Vh   = base + off; off += (size_t)B*T*ADIM;
  float* Uf   = base + off; off += (size_t)B*T*ADIM;
  float* h0a  = base + off; off += B*H;
  float* h0b  = base + off; off += B*H;
  float* h1a  = base + off; off += B*H;
  float* h1b  = base + off; off += B*H;
  float* c0   = base + off; off += B*H;
  float* c1   = base + off; off += B*H;
  float* att0 = base + off; off += B*E;
  float* att1 = base + off; off += B*E;
  float* lstm_in = base + off; off += B*H;
  float* cum  = base + off; off += B*T;
  u16* wf2 = (u16*)(base + off); off += (5*8*16*64*8)/2;
  u16* wf3 = (u16*)(base + off); off += (5*8*16*64*8)/2;

  k_detect<<<1, 256, 0, stream>>>((const uint32_t*)x, dtf);
  int nzero = 6*B*H + 2*B*E + B*H + B*T;
  k_zero<<<(nzero+255)/256, 256, 0, stream>>>(h0a, nzero);
  k_init_prenet<<<1, 256, 0, stream>>>(pw2, pb1, pb2, lstm_in, dtf);
  k_vh<<<B*T, 128, 0, stream>>>(x, attV, Vh, dtf);
  k_repack<<<640, 64, 0, stream>>>(pnw2, wf2, dtf);
  k_repack<<<640, 64, 0, stream>>>(pnw3, wf3, dtf);

  for(int t=0; t<T; t++){
    float* h0r = (t&1)? h0b : h0a;
    float* h0w = (t&1)? h0a : h0b;
    float* h1r = (t&1)? h1b : h1a;
    float* h1w = (t&1)? h1a : h1b;
    float* attr = (t&1)? att1 : att0;
    float* attw = (t&1)? att0 : att1;
    k_lstm<<<1424, 256, 0, stream>>>(wih0, whh0, bih0, bhh0, lstm_in, h0r, c0, h0w,
                                     cum, attF, attU, Uf, dtf);
    k_lstm<<<1024, 256, 0, stream>>>(wih1, whh1, bih1, bhh1, h0w, h1r, c1, h1w,
                                     cum, attF, attU, Uf, dtf);
    k_step_tail<<<32, 256, 0, stream>>>(t, h1w, attr, attw, lstm_in, cum, Vh, Uf, x,
                                        attW, attWb, attv, projw, projb,
                                        pw1, pb1, pw2, pb2, d_out, dtf);
  }
  k_postnet<<<B*T, 256, 0, stream>>>(pnw1, pnb1, wf2, pnb2, wf3, pnb3,
                                     pnw4, pnb4, d_out, dtf);
}